// Round 17
// baseline (95.017 us; speedup 1.0000x reference)
//
#include <hip/hip_runtime.h>
#include <math.h>

// Problem constants
#define BB   4
#define CC   128
#define HH   64
#define WW   64
#define OUTC 128
#define KK   25     // 5x5 attention taps
#define PXB  16     // pixels per block (quarter row)
#define SJ   20     // staged cols: 16 + 4 halo

typedef __attribute__((ext_vector_type(8))) short short8;   // 8 bf16
typedef _Float16 half8  __attribute__((ext_vector_type(8)));
typedef __fp16   fp16x2 __attribute__((ext_vector_type(2))); // cvt_pkrtz ret
typedef __attribute__((ext_vector_type(4))) float floatx4;  // MFMA acc

__device__ __forceinline__ unsigned short f32_to_bf16(float v) {
    unsigned int u = __float_as_uint(v);
    u += 0x7fffu + ((u >> 16) & 1u);          // RNE
    return (unsigned short)(u >> 16);
}

// ---------------------------------------------------------------------------
// Kernel 0 (prep): identical to round 12 (verified).
//  i < 16384:        w2o[o][c] = bf16( sum_r w2[o, c*4+r] )  (o-major, MFMA A)
//  16384..+36864:    w1f = conv1 weights as fp16 in MFMA A-fragment lane
//                    order: w1f[(((dydx*2+mt)*4+ks)*64+lane)*8+i8]
// ---------------------------------------------------------------------------
__global__ void prep_kernel(const float* __restrict__ w2,
                            const float* __restrict__ w1,
                            unsigned short* __restrict__ w2o,
                            unsigned short* __restrict__ w1f) {
    int i = blockIdx.x * 256 + threadIdx.x;
    if (i < 16384) {
        int o = i >> 7, c = i & 127;
        const float* p = w2 + o * (4 * CC) + c * 4;
        w2o[o * CC + c] = f32_to_bf16(p[0] + p[1] + p[2] + p[3]);
    } else if (i < 16384 + 36864) {
        int f = i - 16384;            // 0..36863
        int i8   = f & 7;
        int lane = (f >> 3) & 63;
        int ks   = (f >> 9) & 3;
        int mt   = (f >> 11) & 1;
        int dydx = f >> 12;           // 0..8
        int kk = mt * 16 + (lane & 15);
        int c  = ks * 32 + (lane >> 4) * 8 + i8;
        float v = (kk < KK) ? w1[(size_t)(kk * CC + c) * 9 + dydx] : 0.f;
        _Float16 hv = (_Float16)v;    // RNE
        w1f[f] = *(unsigned short*)&hv;
    }
}

// ---------------------------------------------------------------------------
// Fused kernel: conv1-as-MFMA(fp16) + softmax + attention + MFMA + 2x2 store.
// grid 1024 = (b, h, wq): 16-px quarter-row, 128 threads (2 waves).
// BASE = round 16 (best 94.5). Six structural probes (r10,13,14,15,16) all
// neutral -> latency-rearrangement levers exhausted; only instruction-count
// levers have ever moved this kernel.
//
// THIS ROUND:
//  1. MASK-FOLD: phase C's border masks moved from the x values into the
//     softmax probs (p*(m*x) == (p*m)*x, m in {0,1} -> exact). Removes
//     240 in-loop VALU muls/thread for 50 one-time muls.
//  2. T5 s_setprio(1) around both MFMA clusters (blocks at different
//     phases on a CU -> scheduler can favor the MFMA-issuing wave).
// LDS: xs 15KB + pk 1.6KB = 17KB; sKT overlays xs after conv.
// __launch_bounds__(128,2): 256-reg budget, proven no-spill.
// ---------------------------------------------------------------------------
__global__ __launch_bounds__(128, 2) void fused_kernel(
        const float* __restrict__ x,
        const unsigned short* __restrict__ w1f,
        const unsigned short* __restrict__ w2o,
        const float* __restrict__ b1,
        const float* __restrict__ b2,
        float* __restrict__ out) {
    __shared__ _Float16 xs[3 * SJ * 128];            // 15360 B
    __shared__ float pk[KK * PXB];                   // 1600 B
    unsigned short* sKT = (unsigned short*)xs;       // 16x136 bf16 overlay

    // XCD swizzle (1024 % 8 == 0 -> bijective)
    int bid0 = blockIdx.x;
    int bid  = (bid0 & 7) * 128 + (bid0 >> 3);
    int wq = bid & 3;
    int h  = (bid >> 2) & 63;
    int b  = bid >> 8;
    int t  = threadIdx.x;
    int lane = t & 63;
    int wv = t >> 6;                 // 0..1

    const float* xb = x + (size_t)b * CC * (HH * WW);

    // ---- stage x rows h-1..h+1 as fp16, transposed+swizzled (2-pass) ----
    {
        int jj = lane & 15, cp = lane >> 4;
        int j  = jj + 2;
        int swz = (j & 15) << 3;
        float mr_[3]; int yo_[3];
        #pragma unroll
        for (int r = 0; r < 3; ++r) {
            int y = h - 1 + r;
            mr_[r] = (y >= 0 && y < HH) ? 1.f : 0.f;
            yo_[r] = min(max(y, 0), HH - 1) * WW;
        }
        // pass 1: batch all 48 loads (24 channel-pairs x 3 rows)
        float v0s[24], v1s[24];
        #pragma unroll
        for (int ci = 0; ci < 8; ++ci) {
            int c = wv * 64 + ci * 8 + cp * 2;       // even
            const float* xc0 = xb + (size_t)c * (HH * WW) + wq * 16 + jj;
            const float* xc1 = xc0 + HH * WW;
            #pragma unroll
            for (int r = 0; r < 3; ++r) {
                v0s[ci * 3 + r] = xc0[yo_[r]];
                v1s[ci * 3 + r] = xc1[yo_[r]];
            }
        }
        // pass 2: pack + LDS write
        #pragma unroll
        for (int ci = 0; ci < 8; ++ci) {
            int c  = wv * 64 + ci * 8 + cp * 2;
            int cs = c ^ swz;                        // bit0 preserved
            #pragma unroll
            for (int r = 0; r < 3; ++r) {
                fp16x2 p = __builtin_amdgcn_cvt_pkrtz(
                    v0s[ci * 3 + r] * mr_[r], v1s[ci * 3 + r] * mr_[r]);
                *(fp16x2*)&xs[(r * SJ + j) * 128 + cs] = p;
            }
        }
        // halo cols j in {0,1,18,19} (xcol = 16wq + {-2,-1,16,17}) — 2-pass
        float hv[12], hm[12];
        #pragma unroll
        for (int k = 0; k < 12; ++k) {
            int i  = t + k * 128;
            int jh = i & 3;
            int c  = (i >> 2) & 127;
            int r  = i >> 9;
            int j2 = (jh < 2) ? jh : 16 + jh;
            int xcol = wq * 16 + j2 - 2;
            int y = h - 1 + r;
            bool inb = (xcol >= 0 && xcol < WW && y >= 0 && y < HH);
            int yc  = min(max(y, 0), HH - 1);
            int xc2 = min(max(xcol, 0), WW - 1);
            hv[k] = xb[(size_t)c * (HH * WW) + yc * WW + xc2];
            hm[k] = inb ? 1.f : 0.f;
        }
        #pragma unroll
        for (int k = 0; k < 12; ++k) {
            int i  = t + k * 128;
            int jh = i & 3;
            int c  = (i >> 2) & 127;
            int r  = i >> 9;
            int j2 = (jh < 2) ? jh : 16 + jh;
            xs[(r * SJ + j2) * 128 + (c ^ ((j2 & 15) << 3))] =
                (_Float16)(hv[k] * hm[k]);
        }
    }
    __syncthreads();

    // ---- conv1 via MFMA fp16, dual accumulator chains ----
    int fpx = lane & 15, quad = lane >> 4;
    int mt = wv;
    floatx4 acc0 = {0.f, 0.f, 0.f, 0.f};
    floatx4 acc1 = {0.f, 0.f, 0.f, 0.f};
    __builtin_amdgcn_s_setprio(1);
    #pragma unroll
    for (int dydx = 0; dydx < 9; ++dydx) {
        int r   = dydx / 3;
        int dxm = dydx - 3 * r;
        int j   = fpx + dxm + 1;                 // staged col, 1..18
        int rowbase = (r * SJ + j) * 128;
        int swz = (j & 15) << 3;
        const unsigned short* whb = w1f + (dydx * 2 + mt) * 2048 + lane * 8;
        floatx4& accr = (dydx & 1) ? acc1 : acc0;   // static under unroll
        #pragma unroll
        for (int ks = 0; ks < 4; ++ks) {
            int cb = (ks * 32 + quad * 8) ^ swz;
            half8 A = *(const half8*)(whb + ks * 512);
            half8 B = *(const half8*)&xs[rowbase + cb];
            accr = __builtin_amdgcn_mfma_f32_16x16x32_f16(A, B, accr, 0, 0, 0);
        }
    }
    __builtin_amdgcn_s_setprio(0);
    floatx4 accs = acc0 + acc1;
    #pragma unroll
    for (int reg = 0; reg < 4; ++reg) {          // D row = quad*4+reg
        int kk = mt * 16 + quad * 4 + reg;
        if (kk < KK) pk[kk * PXB + fpx] = accs[reg] + b1[kk];
    }
    __syncthreads();   // pk ready; xs dead -> sKT region reusable

    // ---- phase C: in-register softmax + pipelined attention ----
    // thread = (pp2 = t&7 -> px {2pp2, 2pp2+1}, cw = t>>3 -> 8 chunks of c)
    int pp2 = t & 7, cw = t >> 3;

    // window geometry first (masks needed for the prob fold)
    int colg = wq * 16 + 2 * pp2 - 2;
    int coff[3]; float cmask[3];
    #pragma unroll
    for (int jx = 0; jx < 3; ++jx) {
        int cg = colg + 2 * jx;
        cmask[jx] = (cg >= 0 && cg <= WW - 2) ? 1.f : 0.f;
        coff[jx]  = min(max(cg, 0), WW - 2);
    }
    int yoff[5]; float msk[15];
    #pragma unroll
    for (int di = 0; di < 5; ++di) {
        int y = h + di - 2;
        float rm = (y >= 0 && y < HH) ? 1.f : 0.f;
        yoff[di] = min(max(y, 0), HH - 1) * WW;
        #pragma unroll
        for (int jx = 0; jx < 3; ++jx) msk[di * 3 + jx] = rm * cmask[jx];
    }

    float2 lg[KK];
    #pragma unroll
    for (int k = 0; k < KK; ++k) lg[k] = *(const float2*)&pk[k * PXB + 2 * pp2];
    float m0 = -1e30f, m1 = -1e30f;
    #pragma unroll
    for (int k = 0; k < KK; ++k) { m0 = fmaxf(m0, lg[k].x); m1 = fmaxf(m1, lg[k].y); }
    float s0 = 0.f, s1 = 0.f;
    #pragma unroll
    for (int k = 0; k < KK; ++k) {
        lg[k].x = __expf(lg[k].x - m0); s0 += lg[k].x;
        lg[k].y = __expf(lg[k].y - m1); s1 += lg[k].y;
    }
    float i0 = 1.f / s0, i1 = 1.f / s1;
    #pragma unroll
    for (int k = 0; k < KK; ++k) { lg[k].x *= i0; lg[k].y *= i1; }
    // MASK-FOLD: p*(m*x) == (p*m)*x, m in {0,1} -> exact. Removes the
    // per-chunk mask muls (240/thread) from the pipeline loop below.
    #pragma unroll
    for (int di = 0; di < 5; ++di)
        #pragma unroll
        for (int dj = 0; dj < 5; ++dj) {
            lg[di * 5 + dj].x *= msk[di * 3 + (dj >> 1)];
            lg[di * 5 + dj].y *= msk[di * 3 + ((dj + 1) >> 1)];
        }

#define LOADC(BUF, I8) do {                                            \
    int c_ = (I8) * 16 + cw;                                           \
    const float* xc_ = xb + (size_t)c_ * (HH * WW);                    \
    _Pragma("unroll")                                                  \
    for (int di = 0; di < 5; ++di)                                     \
        _Pragma("unroll")                                              \
        for (int jx = 0; jx < 3; ++jx)                                 \
            BUF[di * 3 + jx] = *(const float2*)(xc_ + yoff[di] + coff[jx]); \
} while (0)

#define COMPST(BUF, I8) do {                                           \
    float t0 = 0.f, t1 = 0.f;                                          \
    _Pragma("unroll")                                                  \
    for (int di = 0; di < 5; ++di) {                                   \
        float2 x01 = BUF[di * 3 + 0];                                  \
        float2 x23 = BUF[di * 3 + 1];                                  \
        float2 x45 = BUF[di * 3 + 2];                                  \
        t0 += lg[di*5+0].x * x01.x + lg[di*5+1].x * x01.y              \
            + lg[di*5+2].x * x23.x + lg[di*5+3].x * x23.y              \
            + lg[di*5+4].x * x45.x;                                    \
        t1 += lg[di*5+0].y * x01.y + lg[di*5+1].y * x23.x              \
            + lg[di*5+2].y * x23.y + lg[di*5+3].y * x45.x              \
            + lg[di*5+4].y * x45.y;                                    \
    }                                                                  \
    int cs_ = (I8) * 16 + cw;                                          \
    sKT[(2 * pp2) * 136 + cs_]     = f32_to_bf16(t0);                  \
    sKT[(2 * pp2 + 1) * 136 + cs_] = f32_to_bf16(t1);                  \
} while (0)

    {
        float2 bufA[15], bufB[15];
        LOADC(bufA, 0);
        LOADC(bufB, 1);
        COMPST(bufA, 0); LOADC(bufA, 2);
        COMPST(bufB, 1); LOADC(bufB, 3);
        COMPST(bufA, 2); LOADC(bufA, 4);
        COMPST(bufB, 3); LOADC(bufB, 5);
        COMPST(bufA, 4); LOADC(bufA, 6);
        COMPST(bufB, 5); LOADC(bufB, 7);
        COMPST(bufA, 6);
        COMPST(bufB, 7);
    }
    __syncthreads();

    // ---- MFMA2: C[o][px] = sum_c W2s[o][c] * s[c][px] ----
    // wave wv owns o-rows [64wv, 64wv+64): 4 o-tiles x 4 ks = 16 MFMA.
    floatx4 am[4] = {{0.f,0.f,0.f,0.f},{0.f,0.f,0.f,0.f},
                     {0.f,0.f,0.f,0.f},{0.f,0.f,0.f,0.f}};
    __builtin_amdgcn_s_setprio(1);
    #pragma unroll
    for (int ks = 0; ks < 4; ++ks) {
        short8 bf = *(const short8*)&sKT[fpx * 136 + ks*32 + quad*8];
        #pragma unroll
        for (int mt2 = 0; mt2 < 4; ++mt2) {
            short8 af = *(const short8*)&w2o[(size_t)(64*wv + 16*mt2 + fpx) * CC
                                             + ks*32 + quad*8];
            am[mt2] = __builtin_amdgcn_mfma_f32_16x16x32_bf16(af, bf, am[mt2], 0, 0, 0);
        }
    }
    __builtin_amdgcn_s_setprio(0);

    // ---- epilogue: D[row=quad*4+reg][col=fpx] + b2, 2x2-replicated write ----
    float* ob = out + (size_t)b * OUTC * (4 * HH * WW);
    int y0 = 2 * h;
    int pxo = wq * 16 + fpx;
    #pragma unroll
    for (int mt2 = 0; mt2 < 4; ++mt2) {
        #pragma unroll
        for (int reg = 0; reg < 4; ++reg) {
            int o = 64*wv + 16*mt2 + quad*4 + reg;
            float v = am[mt2][reg] + b2[o];
            float2 v2 = make_float2(v, v);
            float* r0p = ob + ((size_t)o * (2*HH) + y0) * (2*WW) + 2*pxo;
            *(float2*)(r0p)        = v2;
            *(float2*)(r0p + 2*WW) = v2;
        }
    }
}

// ---------------------------------------------------------------------------
extern "C" void kernel_launch(void* const* d_in, const int* in_sizes, int n_in,
                              void* d_out, int out_size, void* d_ws, size_t ws_size,
                              hipStream_t stream) {
    const float* x  = (const float*)d_in[0];
    const float* w1 = (const float*)d_in[1];
    const float* b1 = (const float*)d_in[2];
    const float* w2 = (const float*)d_in[3];
    const float* b2 = (const float*)d_in[4];
    float* out = (float*)d_out;

    unsigned short* w2o = (unsigned short*)d_ws;               // 32 KB
    unsigned short* w1f = w2o + (size_t)OUTC * CC;             // 72 KB

    prep_kernel<<<(16384 + 36864 + 255) / 256, 256, 0, stream>>>(w2, w1, w2o, w1f);
    fused_kernel<<<BB * HH * 4, 128, 0, stream>>>(x, w1f, w2o, b1, b2, out);
}

// Round 18
// 94.716 us; speedup vs baseline: 1.0032x; 1.0032x over previous
//
#include <hip/hip_runtime.h>
#include <math.h>

// Problem constants
#define BB   4
#define CC   128
#define HH   64
#define WW   64
#define OUTC 128
#define KK   25     // 5x5 attention taps
#define PXB  16     // pixels per block (quarter row)
#define SJ   20     // staged cols: 16 + 4 halo

typedef __attribute__((ext_vector_type(8))) short short8;   // 8 bf16
typedef _Float16 half8  __attribute__((ext_vector_type(8)));
typedef __fp16   fp16x2 __attribute__((ext_vector_type(2))); // cvt_pkrtz ret
typedef __attribute__((ext_vector_type(4))) float floatx4;  // MFMA acc

__device__ __forceinline__ unsigned short f32_to_bf16(float v) {
    unsigned int u = __float_as_uint(v);
    u += 0x7fffu + ((u >> 16) & 1u);          // RNE
    return (unsigned short)(u >> 16);
}

// ---------------------------------------------------------------------------
// Kernel 0 (prep): identical to round 12 (verified).
//  i < 16384:        w2o[o][c] = bf16( sum_r w2[o, c*4+r] )  (o-major, MFMA A)
//  16384..+36864:    w1f = conv1 weights as fp16 in MFMA A-fragment lane
//                    order: w1f[(((dydx*2+mt)*4+ks)*64+lane)*8+i8]
// ---------------------------------------------------------------------------
__global__ void prep_kernel(const float* __restrict__ w2,
                            const float* __restrict__ w1,
                            unsigned short* __restrict__ w2o,
                            unsigned short* __restrict__ w1f) {
    int i = blockIdx.x * 256 + threadIdx.x;
    if (i < 16384) {
        int o = i >> 7, c = i & 127;
        const float* p = w2 + o * (4 * CC) + c * 4;
        w2o[o * CC + c] = f32_to_bf16(p[0] + p[1] + p[2] + p[3]);
    } else if (i < 16384 + 36864) {
        int f = i - 16384;            // 0..36863
        int i8   = f & 7;
        int lane = (f >> 3) & 63;
        int ks   = (f >> 9) & 3;
        int mt   = (f >> 11) & 1;
        int dydx = f >> 12;           // 0..8
        int kk = mt * 16 + (lane & 15);
        int c  = ks * 32 + (lane >> 4) * 8 + i8;
        float v = (kk < KK) ? w1[(size_t)(kk * CC + c) * 9 + dydx] : 0.f;
        _Float16 hv = (_Float16)v;    // RNE
        w1f[f] = *(unsigned short*)&hv;
    }
}

// ---------------------------------------------------------------------------
// Fused kernel: conv1-as-MFMA(fp16, K-split, NO atomics) + softmax +
// attention + MFMA + 2x2 store.
// grid 1024 = (b, h, wq): 16-px quarter-row, 256 threads (4 waves).
//
// OCCUPANCY EXPERIMENT (un-confounded): every config since r2 ran 8
// waves/CU (grid-pinned). r10's 16-waves/CU attempt regressed, but was
// confounded by LDS atomicAdd contention (bank conflicts x7). Here the
// K-split partials go to PRIVATE buffers (pk0 = kh0 + bias, pk1 = kh1;
// rows disjoint per mt) -> plain ds_write, zero atomics. Phase C sums
// pk0+pk1 at read (50 extra LDS reads/thread, trivial). 1024 blocks x
// 4 waves = 16 waves/CU (4/SIMD) = 2x the latency interleave.
//  wave (mt=wv&1, kh=wv>>1): conv D[16kk][16px] over c in [64kh,64kh+64),
//  9 dydx x 2 ks = 18 MFMA.
// LDS: xs 15KB + pk0 1.6KB + pk1 1.6KB = 18.2KB -> 4 blocks/CU (grid cap).
// __launch_bounds__(256,2): r10's identical shape allocated VGPR=72.
// ---------------------------------------------------------------------------
__global__ __launch_bounds__(256, 2) void fused_kernel(
        const float* __restrict__ x,
        const unsigned short* __restrict__ w1f,
        const unsigned short* __restrict__ w2o,
        const float* __restrict__ b1,
        const float* __restrict__ b2,
        float* __restrict__ out) {
    __shared__ _Float16 xs[3 * SJ * 128];            // 15360 B
    __shared__ float pk0[KK * PXB];                  // 1600 B (kh=0 + bias)
    __shared__ float pk1[KK * PXB];                  // 1600 B (kh=1)
    unsigned short* sKT = (unsigned short*)xs;       // 16x136 bf16 overlay

    // XCD swizzle (1024 % 8 == 0 -> bijective)
    int bid0 = blockIdx.x;
    int bid  = (bid0 & 7) * 128 + (bid0 >> 3);
    int wq = bid & 3;
    int h  = (bid >> 2) & 63;
    int b  = bid >> 8;
    int t  = threadIdx.x;
    int lane = t & 63;
    int wv = t >> 6;                 // 0..3

    const float* xb = x + (size_t)b * CC * (HH * WW);

    // ---- stage x rows h-1..h+1 as fp16, transposed+swizzled (2-pass) ----
    {
        int jj = lane & 15, cp = lane >> 4;
        int j  = jj + 2;
        int swz = (j & 15) << 3;
        float mr_[3]; int yo_[3];
        #pragma unroll
        for (int r = 0; r < 3; ++r) {
            int y = h - 1 + r;
            mr_[r] = (y >= 0 && y < HH) ? 1.f : 0.f;
            yo_[r] = min(max(y, 0), HH - 1) * WW;
        }
        // pass 1: batch all 24 loads (12 channel-pairs x ... 4ci x 3r x 2c)
        float v0s[12], v1s[12];
        #pragma unroll
        for (int ci = 0; ci < 4; ++ci) {
            int c = wv * 32 + ci * 8 + cp * 2;       // even
            const float* xc0 = xb + (size_t)c * (HH * WW) + wq * 16 + jj;
            const float* xc1 = xc0 + HH * WW;
            #pragma unroll
            for (int r = 0; r < 3; ++r) {
                v0s[ci * 3 + r] = xc0[yo_[r]];
                v1s[ci * 3 + r] = xc1[yo_[r]];
            }
        }
        // pass 2: pack + LDS write
        #pragma unroll
        for (int ci = 0; ci < 4; ++ci) {
            int c  = wv * 32 + ci * 8 + cp * 2;
            int cs = c ^ swz;                        // bit0 preserved
            #pragma unroll
            for (int r = 0; r < 3; ++r) {
                fp16x2 p = __builtin_amdgcn_cvt_pkrtz(
                    v0s[ci * 3 + r] * mr_[r], v1s[ci * 3 + r] * mr_[r]);
                *(fp16x2*)&xs[(r * SJ + j) * 128 + cs] = p;
            }
        }
        // halo cols j in {0,1,18,19} (xcol = 16wq + {-2,-1,16,17}) — 2-pass
        float hv[6], hm[6];
        #pragma unroll
        for (int k = 0; k < 6; ++k) {
            int i  = t + k * 256;
            int jh = i & 3;
            int c  = (i >> 2) & 127;
            int r  = i >> 9;
            int j2 = (jh < 2) ? jh : 16 + jh;
            int xcol = wq * 16 + j2 - 2;
            int y = h - 1 + r;
            bool inb = (xcol >= 0 && xcol < WW && y >= 0 && y < HH);
            int yc  = min(max(y, 0), HH - 1);
            int xc2 = min(max(xcol, 0), WW - 1);
            hv[k] = xb[(size_t)c * (HH * WW) + yc * WW + xc2];
            hm[k] = inb ? 1.f : 0.f;
        }
        #pragma unroll
        for (int k = 0; k < 6; ++k) {
            int i  = t + k * 256;
            int jh = i & 3;
            int c  = (i >> 2) & 127;
            int r  = i >> 9;
            int j2 = (jh < 2) ? jh : 16 + jh;
            xs[(r * SJ + j2) * 128 + (c ^ ((j2 & 15) << 3))] =
                (_Float16)(hv[k] * hm[k]);
        }
    }
    __syncthreads();

    // ---- conv1 via MFMA fp16, K-split across waves, private partials ----
    int fpx = lane & 15, quad = lane >> 4;
    int mt = wv & 1, kh = wv >> 1;
    floatx4 acc = {0.f, 0.f, 0.f, 0.f};
    __builtin_amdgcn_s_setprio(1);
    #pragma unroll
    for (int dydx = 0; dydx < 9; ++dydx) {
        int r   = dydx / 3;
        int dxm = dydx - 3 * r;
        int j   = fpx + dxm + 1;                 // staged col, 1..18
        int rowbase = (r * SJ + j) * 128;
        int swz = (j & 15) << 3;
        const unsigned short* whb = w1f + (dydx * 2 + mt) * 2048 + lane * 8;
        #pragma unroll
        for (int kq = 0; kq < 2; ++kq) {
            int ks = kh * 2 + kq;
            int cb = (ks * 32 + quad * 8) ^ swz;
            half8 A = *(const half8*)(whb + ks * 512);
            half8 B = *(const half8*)&xs[rowbase + cb];
            acc = __builtin_amdgcn_mfma_f32_16x16x32_f16(A, B, acc, 0, 0, 0);
        }
    }
    __builtin_amdgcn_s_setprio(0);
    {
        float* pkh = kh ? pk1 : pk0;
        #pragma unroll
        for (int reg = 0; reg < 4; ++reg) {      // D row = quad*4+reg
            int kk = mt * 16 + quad * 4 + reg;
            if (kk < KK)
                pkh[kk * PXB + fpx] = acc[reg] + (kh ? 0.f : b1[kk]);
        }
    }
    __syncthreads();   // pk ready; xs dead -> sKT region reusable

    // ---- phase C: in-register softmax + pipelined attention ----
    // thread = (pp2 = t&7 -> px {2pp2, 2pp2+1}, cw = t>>3 -> c lane 0..31)
    int pp2 = t & 7, cw = t >> 3;

    int colg = wq * 16 + 2 * pp2 - 2;
    int coff[3]; float cmask[3];
    #pragma unroll
    for (int jx = 0; jx < 3; ++jx) {
        int cg = colg + 2 * jx;
        cmask[jx] = (cg >= 0 && cg <= WW - 2) ? 1.f : 0.f;
        coff[jx]  = min(max(cg, 0), WW - 2);
    }
    int yoff[5]; float msk[15];
    #pragma unroll
    for (int di = 0; di < 5; ++di) {
        int y = h + di - 2;
        float rm = (y >= 0 && y < HH) ? 1.f : 0.f;
        yoff[di] = min(max(y, 0), HH - 1) * WW;
        #pragma unroll
        for (int jx = 0; jx < 3; ++jx) msk[di * 3 + jx] = rm * cmask[jx];
    }

    float2 lg[KK];
    #pragma unroll
    for (int k = 0; k < KK; ++k) {
        float2 a = *(const float2*)&pk0[k * PXB + 2 * pp2];
        float2 c2 = *(const float2*)&pk1[k * PXB + 2 * pp2];
        lg[k] = make_float2(a.x + c2.x, a.y + c2.y);
    }
    float m0 = -1e30f, m1 = -1e30f;
    #pragma unroll
    for (int k = 0; k < KK; ++k) { m0 = fmaxf(m0, lg[k].x); m1 = fmaxf(m1, lg[k].y); }
    float s0 = 0.f, s1 = 0.f;
    #pragma unroll
    for (int k = 0; k < KK; ++k) {
        lg[k].x = __expf(lg[k].x - m0); s0 += lg[k].x;
        lg[k].y = __expf(lg[k].y - m1); s1 += lg[k].y;
    }
    float i0 = 1.f / s0, i1 = 1.f / s1;
    #pragma unroll
    for (int k = 0; k < KK; ++k) { lg[k].x *= i0; lg[k].y *= i1; }
    // mask-fold (exact): p*(m*x) == (p*m)*x, m in {0,1}
    #pragma unroll
    for (int di = 0; di < 5; ++di)
        #pragma unroll
        for (int dj = 0; dj < 5; ++dj) {
            lg[di * 5 + dj].x *= msk[di * 3 + (dj >> 1)];
            lg[di * 5 + dj].y *= msk[di * 3 + ((dj + 1) >> 1)];
        }

#define LOADC(BUF, I4) do {                                            \
    int c_ = (I4) * 32 + cw;                                           \
    const float* xc_ = xb + (size_t)c_ * (HH * WW);                    \
    _Pragma("unroll")                                                  \
    for (int di = 0; di < 5; ++di)                                     \
        _Pragma("unroll")                                              \
        for (int jx = 0; jx < 3; ++jx)                                 \
            BUF[di * 3 + jx] = *(const float2*)(xc_ + yoff[di] + coff[jx]); \
} while (0)

#define COMPST(BUF, I4) do {                                           \
    float t0 = 0.f, t1 = 0.f;                                          \
    _Pragma("unroll")                                                  \
    for (int di = 0; di < 5; ++di) {                                   \
        float2 x01 = BUF[di * 3 + 0];                                  \
        float2 x23 = BUF[di * 3 + 1];                                  \
        float2 x45 = BUF[di * 3 + 2];                                  \
        t0 += lg[di*5+0].x * x01.x + lg[di*5+1].x * x01.y              \
            + lg[di*5+2].x * x23.x + lg[di*5+3].x * x23.y              \
            + lg[di*5+4].x * x45.x;                                    \
        t1 += lg[di*5+0].y * x01.y + lg[di*5+1].y * x23.x              \
            + lg[di*5+2].y * x23.y + lg[di*5+3].y * x45.x              \
            + lg[di*5+4].y * x45.y;                                    \
    }                                                                  \
    int cs_ = (I4) * 32 + cw;                                          \
    sKT[(2 * pp2) * 136 + cs_]     = f32_to_bf16(t0);                  \
    sKT[(2 * pp2 + 1) * 136 + cs_] = f32_to_bf16(t1);                  \
} while (0)

    {
        float2 bufA[15], bufB[15];
        LOADC(bufA, 0);
        LOADC(bufB, 1);
        COMPST(bufA, 0); LOADC(bufA, 2);
        COMPST(bufB, 1); LOADC(bufB, 3);
        COMPST(bufA, 2);
        COMPST(bufB, 3);
    }
    __syncthreads();

    // ---- MFMA2: C[o][px] = sum_c W2s[o][c] * s[c][px] ----
    // wave wv owns o-rows [32wv, 32wv+32): 2 o-tiles x 4 ks = 8 MFMA.
    floatx4 am[2] = {{0.f,0.f,0.f,0.f},{0.f,0.f,0.f,0.f}};
    __builtin_amdgcn_s_setprio(1);
    #pragma unroll
    for (int ks = 0; ks < 4; ++ks) {
        short8 bf  = *(const short8*)&sKT[fpx * 136 + ks*32 + quad*8];
        short8 af0 = *(const short8*)&w2o[(size_t)(32*wv      + fpx) * CC + ks*32 + quad*8];
        short8 af1 = *(const short8*)&w2o[(size_t)(32*wv + 16 + fpx) * CC + ks*32 + quad*8];
        am[0] = __builtin_amdgcn_mfma_f32_16x16x32_bf16(af0, bf, am[0], 0, 0, 0);
        am[1] = __builtin_amdgcn_mfma_f32_16x16x32_bf16(af1, bf, am[1], 0, 0, 0);
    }
    __builtin_amdgcn_s_setprio(0);

    // ---- epilogue: D[row=quad*4+reg][col=fpx] + b2, 2x2-replicated write ----
    float* ob = out + (size_t)b * OUTC * (4 * HH * WW);
    int y0 = 2 * h;
    int pxo = wq * 16 + fpx;
    #pragma unroll
    for (int mt2 = 0; mt2 < 2; ++mt2) {
        #pragma unroll
        for (int reg = 0; reg < 4; ++reg) {
            int o = 32*wv + 16*mt2 + quad*4 + reg;
            float v = am[mt2][reg] + b2[o];
            float2 v2 = make_float2(v, v);
            float* r0p = ob + ((size_t)o * (2*HH) + y0) * (2*WW) + 2*pxo;
            *(float2*)(r0p)        = v2;
            *(float2*)(r0p + 2*WW) = v2;
        }
    }
}

// ---------------------------------------------------------------------------
extern "C" void kernel_launch(void* const* d_in, const int* in_sizes, int n_in,
                              void* d_out, int out_size, void* d_ws, size_t ws_size,
                              hipStream_t stream) {
    const float* x  = (const float*)d_in[0];
    const float* w1 = (const float*)d_in[1];
    const float* b1 = (const float*)d_in[2];
    const float* w2 = (const float*)d_in[3];
    const float* b2 = (const float*)d_in[4];
    float* out = (float*)d_out;

    unsigned short* w2o = (unsigned short*)d_ws;               // 32 KB
    unsigned short* w1f = w2o + (size_t)OUTC * CC;             // 72 KB

    prep_kernel<<<(16384 + 36864 + 255) / 256, 256, 0, stream>>>(w2, w1, w2o, w1f);
    fused_kernel<<<BB * HH * 4, 256, 0, stream>>>(x, w1f, w2o, b1, b2, out);
}